// Round 7
// baseline (275.996 us; speedup 1.0000x reference)
//
#include <hip/hip_runtime.h>
#include <math.h>

#define NB 4096
#define NC 128
#define NK 32
#define NE 128

typedef __bf16 bf16x8 __attribute__((ext_vector_type(8)));
typedef float floatx4 __attribute__((ext_vector_type(4)));

__device__ __forceinline__ float sigmoidf_(float x){
  if (x >= 0.f){ float z = expf(-x); return 1.f/(1.f+z); }
  float z = expf(x); return z/(1.f+z);
}
__device__ __forceinline__ float softplusf_(float x){
  return fmaxf(x, 0.f) + log1pf(expf(-fabsf(x)));
}
__device__ __forceinline__ unsigned int pack_bf16(float a, float b){
  unsigned short ua = __builtin_bit_cast(unsigned short, (__bf16)a);
  unsigned short ub = __builtin_bit_cast(unsigned short, (__bf16)b);
  return (unsigned int)ua | ((unsigned int)ub << 16);
}

// ---------------- prep: transposes (f32), grouping, consts, W2 MFMA-fragment pack ----------------
// blocks 0..79: w1at/w1bt/ps_w1t transposes; 80..95: grouping; 96: consts+total; 97: w2f
__global__ void k_prep_group(const float* __restrict__ fp_w1, const float* __restrict__ ps_w1,
                             const float* __restrict__ fp_b1, const float* __restrict__ fp_w2,
                             const int* __restrict__ assign, const int* __restrict__ hourp,
                             float* __restrict__ w1at, float* __restrict__ w1bt,
                             float* __restrict__ ps_w1t, int* __restrict__ g,
                             int* __restrict__ row_of, float* __restrict__ w1d_c,
                             float* __restrict__ bzc, uint4* __restrict__ w2f,
                             float* __restrict__ total){
  int bid = blockIdx.x;
  int t = threadIdx.x;
  if (bid < 80){
    int idx = bid*256 + t;
    if (idx < 128*128){
      int o = idx >> 7, e = idx & 127;
      w1at[e*128 + o] = fp_w1[o*258 + e];
      w1bt[e*128 + o] = fp_w1[o*258 + 128 + e];
    } else {
      int i2 = idx - 128*128;
      if (i2 < 128*32){
        int e = i2 >> 5, q = i2 & 31;
        ps_w1t[e*32 + q] = ps_w1[q*128 + e];
      }
    }
  } else if (bid < 96){
    __shared__ int hist[NC];
    __shared__ int loc[256];
    int start = (bid - 80)*256;
    for (int c = t; c < NC; c += 256) hist[c] = 0;
    __syncthreads();
    for (int j = t; j < start; j += 256) atomicAdd(&hist[assign[j]], 1);
    int i = start + t;
    int c = assign[i];
    loc[t] = c;
    __syncthreads();
    int r = hist[c];
    for (int j = 0; j < 256; ++j) r += (j < t && loc[j] == c) ? 1 : 0;
    if (r >= NK) r = NK - 1;
    g[c*NK + r] = i;
    row_of[i] = c*NK + r;
  } else if (bid == 96){
    if (t < 128){
      float hour_f = (float)hourp[0] / 24.0f;
      w1d_c[t] = fp_w1[t*258 + 256];
      bzc[t]   = fmaf(hour_f, fp_w1[t*258 + 257], fp_b1[t]);
    }
    if (t == 128) total[0] = 0.f;
  } else {
    // W2 fragments: frag f=(nt*4+ks)*64+lane holds W2[o=nt*16+(lane&15)][ks*32+(lane>>4)*8 + 0..7]
    for (int ff = t; ff < 1024; ff += 256){
      int lane = ff & 63, fi = ff >> 6;
      int nt = fi >> 2, ks = fi & 3;
      int o = nt*16 + (lane & 15);
      int kb = ks*32 + (lane >> 4)*8;
      const float* src = fp_w2 + o*128 + kb;
      uint4 u;
      u.x = pack_bf16(src[0], src[1]);
      u.y = pack_bf16(src[2], src[3]);
      u.z = pack_bf16(src[4], src[5]);
      u.w = pack_bf16(src[6], src[7]);
      w2f[ff] = u;
    }
  }
}

// ---------------- fused per-cluster kernel: prio + hij + pflow(MFMA) + eff + greedy -----------
// One block per cluster (128 x 256). All intermediates in LDS; numerics bit-identical to R6:
//   - prio: same fmaf chain over e ascending, same shfl_xor tree, sigmoid       -> prio_l
//   - hij: same nested-fmaf 4-e blocks (f32, precision-critical)                -> his/hjs (LDS)
//   - pflow: same (hi+hj)+fmaf(d,wd,bz) -> relu -> single bf16 round -> MFMA    -> pf_s (LDS)
//   - greedy: same prefix-scan allocation, writes fl_c/ef_c direct to global
__global__ __launch_bounds__(256, 1) void k_cluster(
    const float* __restrict__ emb, const float* __restrict__ gen,
    const float* __restrict__ cons, const float* __restrict__ pos,
    const float* __restrict__ ps_w1t, const float* __restrict__ ps_b1,
    const float* __restrict__ ps_w2, const float* __restrict__ ps_b2,
    const float* __restrict__ w1at, const float* __restrict__ w1bt,
    const float* __restrict__ w1d_c, const float* __restrict__ bzc,
    const uint4* __restrict__ w2f, const float* __restrict__ fp_b2,
    const float* __restrict__ fp_w3, const float* __restrict__ fp_b3,
    const float* __restrict__ en_w1, const float* __restrict__ en_b1,
    const float* __restrict__ en_w2, const float* __restrict__ en_b2,
    const int* __restrict__ g, const int* __restrict__ hourp,
    float* __restrict__ fl_c, float* __restrict__ ef_c, float* __restrict__ total,
    float* __restrict__ esent, float* __restrict__ erecv, float* __restrict__ nafter){
  __shared__ float his[32*128];     // hi rows (broadcast-read -> no pad needed)
  __shared__ float hjs[32*132];     // hj rows (16-row gathers -> pad to 132 for 2-way banks)
  __shared__ float pf_s[1024];
  __shared__ float ef_s[1024];
  __shared__ float px[32], py[32], netl[32], prio_l[32];
  __shared__ int gl[32];
  __shared__ int order_s[32];
  int t = threadIdx.x;
  int c = blockIdx.x;
  int lane = t & 63, wv = t >> 6;

  // ---- phase 0: gather cluster metadata ----
  if (t < 32){
    int b = g[c*NK + t];
    gl[t] = b;
    px[t] = pos[2*b];
    py[t] = pos[2*b + 1];
    int h = hourp[0];
    netl[t] = gen[b*24 + h] - cons[b*24 + h];
  }
  __syncthreads();

  // ---- phase 1: prio MLP (f32 exact, same as R6 k_prio) ----
  {
    int q = t & 31;
    int bsub = t >> 5;
    for (int bb = 0; bb < 4; ++bb){
      int b = bb*8 + bsub;
      const float* er = emb + gl[b]*128;
      float acc = ps_b1[q];
      for (int e = 0; e < 128; ++e) acc = fmaf(er[e], ps_w1t[e*32 + q], acc);
      float v = fmaxf(acc, 0.f) * ps_w2[q];
      for (int m = 16; m >= 1; m >>= 1) v += __shfl_xor(v, m, 32);
      if (q == 0) prio_l[b] = sigmoidf_(v + ps_b2[0]);
    }
  }

  // ---- phase 2: hij GEMM (f32 exact, same fmaf nesting as R6 k_hij) ----
  // wave wv: rows wv*8..+8; thread cols {lane, lane+64} for both hi and hj
  {
    int r0 = wv*8;
    int gr[8];
#pragma unroll
    for (int r = 0; r < 8; ++r) gr[r] = gl[r0 + r];
    float a0[8], a1[8], c0[8], c1[8];
#pragma unroll
    for (int r = 0; r < 8; ++r){ a0[r]=0.f; a1[r]=0.f; c0[r]=0.f; c1[r]=0.f; }
    for (int e = 0; e < 128; e += 4){
      float wa00 = w1at[(e+0)*128 + lane],      wa01 = w1at[(e+1)*128 + lane];
      float wa02 = w1at[(e+2)*128 + lane],      wa03 = w1at[(e+3)*128 + lane];
      float wa10 = w1at[(e+0)*128 + lane + 64], wa11 = w1at[(e+1)*128 + lane + 64];
      float wa12 = w1at[(e+2)*128 + lane + 64], wa13 = w1at[(e+3)*128 + lane + 64];
      float wb00 = w1bt[(e+0)*128 + lane],      wb01 = w1bt[(e+1)*128 + lane];
      float wb02 = w1bt[(e+2)*128 + lane],      wb03 = w1bt[(e+3)*128 + lane];
      float wb10 = w1bt[(e+0)*128 + lane + 64], wb11 = w1bt[(e+1)*128 + lane + 64];
      float wb12 = w1bt[(e+2)*128 + lane + 64], wb13 = w1bt[(e+3)*128 + lane + 64];
#pragma unroll
      for (int r = 0; r < 8; ++r){
        float4 ev = *(const float4*)&emb[gr[r]*128 + e];
        a0[r] = fmaf(ev.x, wa00, fmaf(ev.y, wa01, fmaf(ev.z, wa02, fmaf(ev.w, wa03, a0[r]))));
        a1[r] = fmaf(ev.x, wa10, fmaf(ev.y, wa11, fmaf(ev.z, wa12, fmaf(ev.w, wa13, a1[r]))));
        c0[r] = fmaf(ev.x, wb00, fmaf(ev.y, wb01, fmaf(ev.z, wb02, fmaf(ev.w, wb03, c0[r]))));
        c1[r] = fmaf(ev.x, wb10, fmaf(ev.y, wb11, fmaf(ev.z, wb12, fmaf(ev.w, wb13, c1[r]))));
      }
    }
#pragma unroll
    for (int r = 0; r < 8; ++r){
      his[(r0+r)*128 + lane]      = a0[r];
      his[(r0+r)*128 + lane + 64] = a1[r];
      hjs[(r0+r)*132 + lane]      = c0[r];
      hjs[(r0+r)*132 + lane + 64] = c1[r];
    }
  }
  __syncthreads();

  // ---- phase 3: pflow via MFMA (same arithmetic as R6 k_pflow) ----
  {
    int l16 = lane & 15, quad = lane >> 4;
    int j0 = (wv >> 1)*16;
    int j = j0 + l16;
    bf16x8 bfr[4][4];
#pragma unroll
    for (int nt = 0; nt < 4; ++nt)
#pragma unroll
      for (int ks = 0; ks < 4; ++ks)
        bfr[nt][ks] = __builtin_bit_cast(bf16x8, w2f[(nt*4 + ks)*64 + lane]);
    float4 hjv[8], wdv[8], bzv[8];
#pragma unroll
    for (int ks = 0; ks < 4; ++ks){
      int q8 = ks*8 + quad*2;
      hjv[ks*2+0] = *(const float4*)&hjs[j*132 + q8*4];
      hjv[ks*2+1] = *(const float4*)&hjs[j*132 + q8*4 + 4];
      wdv[ks*2+0] = ((const float4*)w1d_c)[q8];
      wdv[ks*2+1] = ((const float4*)w1d_c)[q8 + 1];
      bzv[ks*2+0] = ((const float4*)bzc)[q8];
      bzv[ks*2+1] = ((const float4*)bzc)[q8 + 1];
    }
    float b2v[4], w3v[4];
#pragma unroll
    for (int nt = 0; nt < 4; ++nt){
      b2v[nt] = fp_b2[nt*16 + l16];
      w3v[nt] = fp_w3[nt*16 + l16];
    }
    float b3 = fp_b3[0];
    float xj = px[j], yj = py[j];
    for (int it = 0; it < 16; ++it){
      int i = (wv & 1) + it*2;
      float dx = px[i] - xj, dy = py[i] - yj;
      float d = sqrtf(fmaf(dx, dx, dy*dy));
      bf16x8 af[4];
#pragma unroll
      for (int ks = 0; ks < 4; ++ks){
        int q8 = ks*8 + quad*2;
        float4 h0 = *(const float4*)&his[i*128 + q8*4];
        float4 h1 = *(const float4*)&his[i*128 + q8*4 + 4];
        float4 j0v = hjv[ks*2], j1v = hjv[ks*2+1];
        float4 w0 = wdv[ks*2], w1 = wdv[ks*2+1];
        float4 z0 = bzv[ks*2], z1 = bzv[ks*2+1];
        float v0 = fmaxf(h0.x + j0v.x + fmaf(d, w0.x, z0.x), 0.f);
        float v1 = fmaxf(h0.y + j0v.y + fmaf(d, w0.y, z0.y), 0.f);
        float v2 = fmaxf(h0.z + j0v.z + fmaf(d, w0.z, z0.z), 0.f);
        float v3 = fmaxf(h0.w + j0v.w + fmaf(d, w0.w, z0.w), 0.f);
        float v4 = fmaxf(h1.x + j1v.x + fmaf(d, w1.x, z1.x), 0.f);
        float v5 = fmaxf(h1.y + j1v.y + fmaf(d, w1.y, z1.y), 0.f);
        float v6 = fmaxf(h1.z + j1v.z + fmaf(d, w1.z, z1.z), 0.f);
        float v7 = fmaxf(h1.w + j1v.w + fmaf(d, w1.w, z1.w), 0.f);
        uint4 u;
        u.x = pack_bf16(v0, v1);
        u.y = pack_bf16(v2, v3);
        u.z = pack_bf16(v4, v5);
        u.w = pack_bf16(v6, v7);
        af[ks] = __builtin_bit_cast(bf16x8, u);
      }
      floatx4 acc[4];
#pragma unroll
      for (int nt = 0; nt < 4; ++nt){
        acc[nt] = (floatx4){0.f, 0.f, 0.f, 0.f};
#pragma unroll
        for (int ks = 0; ks < 4; ++ks)
          acc[nt] = __builtin_amdgcn_mfma_f32_16x16x32_bf16(af[ks], bfr[nt][ks], acc[nt], 0, 0, 0);
      }
#pragma unroll
      for (int r = 0; r < 4; ++r){
        float s = 0.f;
#pragma unroll
        for (int nt = 0; nt < 4; ++nt)
          s = fmaf(fmaxf(acc[nt][r] + b2v[nt], 0.f), w3v[nt], s);
#pragma unroll
        for (int m = 8; m >= 1; m >>= 1) s += __shfl_xor(s, m);
        if (l16 == 0)
          pf_s[i*32 + j0 + quad*4 + r] = softplusf_(s + b3);
      }
    }
  }
  __syncthreads();

  // ---- phase 4: efficiency tile + priority ranks (same arithmetic as R6 k_greedy) ----
  for (int e = t; e < 1024; e += 256){
    int ii = e >> 5, jj = e & 31;
    float dx = px[ii] - px[jj], dy = py[ii] - py[jj];
    float d = sqrtf(fmaf(dx, dx, dy*dy));
    float ds = d * (1.0f/1000.0f);
    float acc = en_b2[0];
#pragma unroll
    for (int q = 0; q < 16; ++q)
      acc = fmaf(fmaxf(fmaf(ds, en_w1[q], en_b1[q]), 0.f), en_w2[q], acc);
    ef_s[e] = 0.85f + 0.13f*sigmoidf_(acc);
  }
  if (t < 64){
    int tl = t & 31;
    float p = (t < 32) ? prio_l[t] : -1e30f;
    int rank = 0;
    for (int k = 0; k < 32; ++k){
      float pk = __shfl(p, k, 32);
      rank += ((pk > p) || (pk == p && k < tl)) ? 1 : 0;
    }
    if (t < 32) order_s[rank] = t;
  }
  __syncthreads();

  // ---- phase 5: greedy allocation (wave 0 only; same prefix-scan form as R6) ----
  if (t < 64){
    int tl = t & 31;
    int b = order_s[tl];
    float net0 = netl[b];
    float dnet = net0;
    float recv = 0.f;
    float ctotal = 0.f;
    for (int i = 0; i < 32; ++i){
      int a = order_s[i];
      float av0 = fmaxf(__shfl(net0, i, 32), 0.f);
      float pf = pf_s[a*32 + b];
      float ef = ef_s[a*32 + b];
      float needed = -dnet;
      float m = (needed > 0.f) ? fminf(needed, pf) : 0.f;
      float s = m;
#pragma unroll
      for (int dd = 1; dd < 32; dd <<= 1){
        float u = __shfl_up(s, dd, 32);
        if (tl >= dd) s += u;
      }
      float Se = __shfl_up(s, 1, 32);
      if (tl == 0) Se = 0.f;
      float rprev = fmaxf(av0 - Se, 0.f);
      int act = (rprev > 0.f) && (needed > 0.f);
      float f = fminf(m, rprev);
      dnet = fmaf(f, ef, dnet);
      recv = fmaf(f, ef, recv);
      if (t < 32){
        fl_c[c*1024 + a*32 + b] = f;
        ef_c[c*1024 + a*32 + b] = act ? ef : 1.0f;
      }
      float rs = f;
      for (int mm = 16; mm >= 1; mm >>= 1) rs += __shfl_xor(rs, mm, 32);
      if (t == 0){ esent[gl[a]] = rs; ctotal += rs; }
    }
    if (t < 32){
      nafter[gl[b]] = dnet;
      erecv[gl[b]]  = recv;
    }
    if (t == 0) atomicAdd(total, ctotal);
  }
}

// ---------------- stream N x N outputs: build each row in LDS, write once ----------------
__global__ __launch_bounds__(256) void k_write(
    const float* __restrict__ fl_c, const float* __restrict__ ef_c,
    const int* __restrict__ g, const int* __restrict__ row_of,
    float* __restrict__ sharing, float* __restrict__ effm){
  __shared__ float rowS[4096];
  __shared__ float rowE[4096];
  __shared__ int   cols[32];
  __shared__ float vals[32];
  __shared__ float vale[32];
  int t = threadIdx.x;
  int r = blockIdx.x;
  int ra = row_of[r];
  int c = ra >> 5, a = ra & 31;
  if (t < 32){
    cols[t] = g[c*NK + t];
    vals[t] = fl_c[c*1024 + a*32 + t];
    vale[t] = ef_c[c*1024 + a*32 + t];
  }
  float4 z4 = make_float4(0.f, 0.f, 0.f, 0.f);
  float4 o4 = make_float4(1.f, 1.f, 1.f, 1.f);
  float4* s4 = (float4*)rowS;
  float4* e4 = (float4*)rowE;
#pragma unroll
  for (int q = 0; q < 4; ++q){ s4[t + 256*q] = z4; e4[t + 256*q] = o4; }
  __syncthreads();
  if (t < 32){ rowS[cols[t]] = vals[t]; rowE[cols[t]] = vale[t]; }
  __syncthreads();
  float4* gs = (float4*)(sharing + (long)r*NB);
  float4* ge = (float4*)(effm    + (long)r*NB);
#pragma unroll
  for (int q = 0; q < 4; ++q){ gs[t + 256*q] = s4[t + 256*q]; ge[t + 256*q] = e4[t + 256*q]; }
}

extern "C" void kernel_launch(void* const* d_in, const int* in_sizes, int n_in,
                              void* d_out, int out_size, void* d_ws, size_t ws_size,
                              hipStream_t stream){
  (void)in_sizes; (void)n_in; (void)out_size; (void)ws_size;
  const float* emb   = (const float*)d_in[0];
  const float* gen   = (const float*)d_in[1];
  const float* cons  = (const float*)d_in[2];
  const float* pos   = (const float*)d_in[3];
  const float* fp_w1 = (const float*)d_in[4];
  const float* fp_b1 = (const float*)d_in[5];
  const float* fp_w2 = (const float*)d_in[6];
  const float* fp_b2 = (const float*)d_in[7];
  const float* fp_w3 = (const float*)d_in[8];
  const float* fp_b3 = (const float*)d_in[9];
  const float* en_w1 = (const float*)d_in[10];
  const float* en_b1 = (const float*)d_in[11];
  const float* en_w2 = (const float*)d_in[12];
  const float* en_b2 = (const float*)d_in[13];
  const float* ps_w1 = (const float*)d_in[14];
  const float* ps_b1 = (const float*)d_in[15];
  const float* ps_w2 = (const float*)d_in[16];
  const float* ps_b2 = (const float*)d_in[17];
  const int*   assign = (const int*)d_in[18];
  const int*   hourp  = (const int*)d_in[20];

  // Workspace map (audited, no overlaps):
  char* ws = (char*)d_ws;
  float* w1at   = (float*)(ws + 0);           // 64 KB   [0,      65536)
  float* w1bt   = (float*)(ws + 65536);       // 64 KB   [65536,  131072)
  float* ps_w1t = (float*)(ws + 131072);      // 16 KB   [131072, 147456)
  int*   g      = (int*)  (ws + 147456);      // 16 KB   [147456, 163840)
  int*   row_of = (int*)  (ws + 163840);      // 16 KB   [163840, 180224)
  float* w1d_c  = (float*)(ws + 180224);      // 512 B   [180224, 180736)
  float* bzc    = (float*)(ws + 180736);      // 512 B   [180736, 181248)
  uint4* w2f    = (uint4*)(ws + 181248);      // 16 KB   [181248, 197632)
  float* fl_c   = (float*)(ws + 262144);      // 512 KB  [262144, 786432)
  float* ef_c   = (float*)(ws + 786432);      // 512 KB  [786432, 1310720)

  float* sharing = (float*)d_out;
  float* effm    = sharing + (long)NB*NB;
  float* total   = effm + (long)NB*NB;
  float* esent   = total + 1;
  float* erecv   = esent + NB;
  float* nafter  = erecv + NB;

  hipLaunchKernelGGL(k_prep_group, dim3(98), dim3(256), 0, stream,
                     fp_w1, ps_w1, fp_b1, fp_w2, assign, hourp,
                     w1at, w1bt, ps_w1t, g, row_of, w1d_c, bzc, w2f, total);
  hipLaunchKernelGGL(k_cluster, dim3(128), dim3(256), 0, stream,
                     emb, gen, cons, pos, ps_w1t, ps_b1, ps_w2, ps_b2,
                     w1at, w1bt, w1d_c, bzc, w2f, fp_b2, fp_w3, fp_b3,
                     en_w1, en_b1, en_w2, en_b2, g, hourp,
                     fl_c, ef_c, total, esent, erecv, nafter);
  hipLaunchKernelGGL(k_write, dim3(4096), dim3(256), 0, stream,
                     fl_c, ef_c, g, row_of, sharing, effm);
}